// Round 16
// baseline (400.324 us; speedup 1.0000x reference)
//
#include <hip/hip_runtime.h>
#include <hip/hip_bf16.h>
#include <math.h>

// Problem constants
#define NHD 8
#define DH 32
#define CC 256
#define NTOK 4096
#define BATCH 4
#define MTOT 16384

typedef __attribute__((ext_vector_type(8))) short short8;
typedef __attribute__((ext_vector_type(4))) short s16x4;
typedef __attribute__((ext_vector_type(4))) float f32x4;
typedef __attribute__((ext_vector_type(16))) float f32x16;
typedef __attribute__((ext_vector_type(2))) unsigned int u32x2;

#if __has_builtin(__builtin_amdgcn_exp2f)
#define EXP2F __builtin_amdgcn_exp2f
#else
#define EXP2F exp2f
#endif

__device__ inline float bf2f(short s) {
    unsigned int u = ((unsigned int)(unsigned short)s) << 16;
    float f; __builtin_memcpy(&f, &u, 4); return f;
}
__device__ inline short f2bf(float f) {
    __hip_bfloat16 h = __float2bfloat16(f);
    unsigned short u; __builtin_memcpy(&u, &h, 2); return (short)u;
}
// pack two f32 -> one u32 of 2 bf16 (low = lo); plain C, compiler lowers well (m240)
__device__ inline unsigned int pack2(float lo, float hi) {
    unsigned int a = (unsigned short)f2bf(lo);
    unsigned int b = (unsigned short)f2bf(hi);
    return a | (b << 16);
}
__device__ inline short8 mk8(unsigned int a, unsigned int b, unsigned int c, unsigned int d) {
    unsigned int t[4] = {a, b, c, d};
    short8 r; __builtin_memcpy(&r, t, 16); return r;
}

// ---------------- conversion kernels ----------------
__global__ __launch_bounds__(256) void conv_x_kernel(const float* __restrict__ src,
                                                     short* __restrict__ dst, int n8) {
    int t = blockIdx.x * 256 + threadIdx.x;
    if (t >= n8) return;
    const f32x4* s4 = (const f32x4*)src;
    f32x4 a = s4[t * 2], b = s4[t * 2 + 1];
    short8 o;
    o[0] = f2bf(a[0]); o[1] = f2bf(a[1]); o[2] = f2bf(a[2]); o[3] = f2bf(a[3]);
    o[4] = f2bf(b[0]); o[5] = f2bf(b[1]); o[6] = f2bf(b[2]); o[7] = f2bf(b[3]);
    ((short8*)dst)[t] = o;
}

__global__ __launch_bounds__(256) void conv_w_kernel(const float* __restrict__ Wq,
                                                     const float* __restrict__ Wk,
                                                     const float* __restrict__ Wv,
                                                     const float* __restrict__ Wo,
                                                     short* __restrict__ dst) {
    int w = blockIdx.y;
    const float* src = (w == 0) ? Wq : (w == 1) ? Wk : (w == 2) ? Wv : Wo;
    int t = blockIdx.x * 256 + threadIdx.x;
    const f32x4* s4 = (const f32x4*)src;
    f32x4 a = s4[t * 2], b = s4[t * 2 + 1];
    short8 o;
    o[0] = f2bf(a[0]); o[1] = f2bf(a[1]); o[2] = f2bf(a[2]); o[3] = f2bf(a[3]);
    o[4] = f2bf(b[0]); o[5] = f2bf(b[1]); o[6] = f2bf(b[2]); o[7] = f2bf(b[3]);
    ((short8*)(dst + w * 65536))[t] = o;
}

// ---------------- QKV projection GEMM ----------------
// y = x @ W^T + b.  Q pre-scaled by (1/sqrt(dh))*log2(e) -> attn uses exp2 directly.
__global__ __launch_bounds__(256) void qkv_kernel(const short* __restrict__ xb,
                                                  const short* __restrict__ Wb,
                                                  const float* __restrict__ bq,
                                                  const float* __restrict__ bk,
                                                  const float* __restrict__ bv,
                                                  short* __restrict__ Qb,
                                                  short* __restrict__ Kb,
                                                  short* __restrict__ Vt,
                                                  short* __restrict__ Vres) {
    int wsel = blockIdx.y;
    const short* W = Wb + wsel * 65536;
    int wave = threadIdx.x >> 6;
    int lane = threadIdx.x & 63;
    int lo = lane & 15, hi = lane >> 4;
    int m0 = blockIdx.x * 64 + wave * 16;

    f32x4 acc[16];
#pragma unroll
    for (int i = 0; i < 16; i++) acc[i] = (f32x4){0, 0, 0, 0};

    for (int ks = 0; ks < 8; ks++) {
        short8 a = *(const short8*)(xb + (m0 + lo) * 256 + ks * 32 + hi * 8);
#pragma unroll
        for (int nf = 0; nf < 16; nf++) {
            short8 b = *(const short8*)(W + (nf * 16 + lo) * 256 + ks * 32 + hi * 8);
            acc[nf] = __builtin_amdgcn_mfma_f32_16x16x32_bf16(a, b, acc[nf], 0, 0, 0);
        }
    }
    const float* bias = (wsel == 0) ? bq : (wsel == 1) ? bk : bv;
    const float qscale = 0.17677669529663687f * 1.4426950408889634f;
#pragma unroll
    for (int nf = 0; nf < 16; nf++) {
#pragma unroll
        for (int r = 0; r < 4; r++) {
            int m = m0 + hi * 4 + r;
            int c = nf * 16 + lo;
            float v = acc[nf][r] + bias[c];
            int bb = m >> 12, n = m & 4095;
            int h = c >> 5, d = c & 31;
            int bh = bb * 8 + h;
            if (wsel == 0)      Qb[(bh * 4096 + n) * 32 + d] = f2bf(v * qscale);
            else if (wsel == 1) Kb[(bh * 4096 + n) * 32 + d] = f2bf(v);
            else {
                short s = f2bf(v);
                Vt[(bh * 32 + d) * 4096 + n] = s;   // transposed per head (PV A-operand)
                Vres[m * 256 + c] = s;              // row-major for residual
            }
        }
    }
}

// ------- flash attention v3: 32x32 MFMA, in-register P, in-WG split-KV, defer-max -------
// Grid: 32 bh * 64 qpair = 2048 WGs, 4 waves = 2 q-tiles x 2 kv-halves -> 8192 waves (100% occ).
// Each wave: 32 q-rows, kv in [half*2048, half*2048+2048), KV tile = 32.
// S^T = mfma_32x32x16(K, Q): lane owns q-col = lane&31, 16 kv rows (reg&3)+8*(reg>>2)+4*lh.
// Defer-max: rescale only when a new running max appears (wave-uniform __any).
// P relayout for PV B-operand via permlane32_swap. Final: exact flash-merge of the
// two kv-halves through LDS, then bf16 store.
__global__ __launch_bounds__(256, 8) void attn_kernel(const short* __restrict__ Qb,
                                                      const short* __restrict__ Kb,
                                                      const short* __restrict__ Vt,
                                                      short* __restrict__ O) {
    __shared__ float Osh[2][2][32][33];   // [tile][half][q][d] padded
    __shared__ float Msh[2][2][32];
    __shared__ float Lsh[2][2][32];

    int bx = blockIdx.x;
    int bh = bx >> 6;
    int qbase = (bx & 63) * 64;
    int wave = threadIdx.x >> 6, lane = threadIdx.x & 63;
    int tile = wave >> 1, half = wave & 1;
    int l31 = lane & 31, lh = lane >> 5;
    int q0 = qbase + tile * 32;

    const short* Qrow = Qb + (bh * 4096 + q0 + l31) * 32;
    short8 bq0 = *(const short8*)(Qrow + lh * 8);        // d 0-15 slice
    short8 bq1 = *(const short8*)(Qrow + 16 + lh * 8);   // d 16-31 slice

    const short* Kh   = Kb + bh * 131072 + half * 65536;            // kv-half base
    const short* Vrow = Vt + (bh * 32 + l31) * 4096 + half * 2048;  // A=V^T row d=l31

    float mr = -1e30f, lr = 0.f;
    f32x16 oacc;
#pragma unroll
    for (int i = 0; i < 16; i++) oacc[i] = 0.f;

    for (int kv0 = 0; kv0 < 2048; kv0 += 32) {
        const short* Krow = Kh + (kv0 + l31) * 32;
        short8 ak0 = *(const short8*)(Krow + lh * 8);
        short8 ak1 = *(const short8*)(Krow + 16 + lh * 8);
        short8 av0 = *(const short8*)(Vrow + kv0 + lh * 8);
        short8 av1 = *(const short8*)(Vrow + kv0 + 16 + lh * 8);

        f32x16 s;
#pragma unroll
        for (int i = 0; i < 16; i++) s[i] = 0.f;
        s = __builtin_amdgcn_mfma_f32_32x32x16_bf16(ak0, bq0, s, 0, 0, 0);
        s = __builtin_amdgcn_mfma_f32_32x32x16_bf16(ak1, bq1, s, 0, 0, 0);

        // col max via max3-friendly triples + cross-half shfl
        float t0 = fmaxf(fmaxf(s[0], s[1]), s[2]);
        float t1 = fmaxf(fmaxf(s[3], s[4]), s[5]);
        float t2 = fmaxf(fmaxf(s[6], s[7]), s[8]);
        float t3 = fmaxf(fmaxf(s[9], s[10]), s[11]);
        float t4 = fmaxf(fmaxf(s[12], s[13]), s[14]);
        float mx = fmaxf(fmaxf(fmaxf(t0, t1), fmaxf(t2, t3)), fmaxf(t4, s[15]));
        mx = fmaxf(mx, __shfl_xor(mx, 32, 64));

        // defer-max: only rescale when a new running max appears (exact, THR=0)
        if (__any(mx > mr)) {
            float mnew = fmaxf(mr, mx);
            float al = EXP2F(mr - mnew);
            mr = mnew;
            lr *= al;
#pragma unroll
            for (int i = 0; i < 16; i++) oacc[i] *= al;
        }

        float p[16];
#pragma unroll
        for (int i = 0; i < 16; i++) p[i] = EXP2F(s[i] - mr);

        float r0 = (p[0] + p[1]) + (p[2] + p[3]);
        float r1 = (p[4] + p[5]) + (p[6] + p[7]);
        float r2 = (p[8] + p[9]) + (p[10] + p[11]);
        float r3 = (p[12] + p[13]) + (p[14] + p[15]);
        float rs = (r0 + r1) + (r2 + r3);
        rs += __shfl_xor(rs, 32, 64);
        lr += rs;

        // pack P to bf16 words; quad j covers kv = 8j + 4lh + {0..3}
        unsigned int w0 = pack2(p[0], p[1]),   w1 = pack2(p[2], p[3]);
        unsigned int w2 = pack2(p[4], p[5]),   w3 = pack2(p[6], p[7]);
        unsigned int w4 = pack2(p[8], p[9]),   w5 = pack2(p[10], p[11]);
        unsigned int w6 = pack2(p[12], p[13]), w7 = pack2(p[14], p[15]);
        short8 pb1, pb2;
#if __has_builtin(__builtin_amdgcn_permlane32_swap)
        u32x2 a0 = __builtin_amdgcn_permlane32_swap(w0, w2, false, false);
        u32x2 a1 = __builtin_amdgcn_permlane32_swap(w1, w3, false, false);
        u32x2 a2 = __builtin_amdgcn_permlane32_swap(w4, w6, false, false);
        u32x2 a3 = __builtin_amdgcn_permlane32_swap(w5, w7, false, false);
        pb1 = mk8(a0[0], a1[0], a0[1], a1[1]);
        pb2 = mk8(a2[0], a3[0], a2[1], a3[1]);
#else
        unsigned int x0 = __shfl_xor(w0, 32, 64), x1 = __shfl_xor(w1, 32, 64);
        unsigned int x2 = __shfl_xor(w2, 32, 64), x3 = __shfl_xor(w3, 32, 64);
        unsigned int x4 = __shfl_xor(w4, 32, 64), x5 = __shfl_xor(w5, 32, 64);
        unsigned int x6 = __shfl_xor(w6, 32, 64), x7 = __shfl_xor(w7, 32, 64);
        pb1 = mk8(lh ? x2 : w0, lh ? x3 : w1, lh ? w2 : x0, lh ? w3 : x1);
        pb2 = mk8(lh ? x6 : w4, lh ? x7 : w5, lh ? w6 : x4, lh ? w7 : x5);
#endif

        oacc = __builtin_amdgcn_mfma_f32_32x32x16_bf16(av0, pb1, oacc, 0, 0, 0);
        oacc = __builtin_amdgcn_mfma_f32_32x32x16_bf16(av1, pb2, oacc, 0, 0, 0);
    }

    // stash partial (unnormalized O, m, l) in LDS
#pragma unroll
    for (int j = 0; j < 4; j++)
#pragma unroll
        for (int t = 0; t < 4; t++)
            Osh[tile][half][l31][8 * j + 4 * lh + t] = oacc[4 * j + t];
    if (lh == 0) { Msh[tile][half][l31] = mr; Lsh[tile][half][l31] = lr; }
    __syncthreads();

    // exact flash-merge of the two halves; 256 threads cover 2 tiles x 32 q x 4 d-groups
    int t = threadIdx.x;
    int mt = t >> 7;
    int idx = t & 127;
    int q = idx >> 2;
    int d0 = (idx & 3) * 8;
    float m0 = Msh[mt][0][q], m1 = Msh[mt][1][q];
    float l0 = Lsh[mt][0][q], l1 = Lsh[mt][1][q];
    float mstar = fmaxf(m0, m1);
    float e0 = EXP2F(m0 - mstar), e1 = EXP2F(m1 - mstar);
    float inv = 1.0f / (l0 * e0 + l1 * e1);
    int token = (bh >> 3) * 4096 + qbase + mt * 32 + q;
    int c0 = (bh & 7) * 32 + d0;
    short8 ow;
#pragma unroll
    for (int u = 0; u < 8; u++) {
        float o = (Osh[mt][0][q][d0 + u] * e0 + Osh[mt][1][q][d0 + u] * e1) * inv;
        ow[u] = f2bf(o);
    }
    *(short8*)(O + token * 256 + c0) = ow;
}

// ---------------- out-proj + bias + residual + LayerNorm ----------------
__global__ __launch_bounds__(256) void proj_ln_kernel(const short* __restrict__ O,
                                                      const short* __restrict__ Wob,
                                                      const float* __restrict__ bo,
                                                      const short* __restrict__ Vres,
                                                      const float* __restrict__ gamma,
                                                      const float* __restrict__ beta,
                                                      float* __restrict__ out) {
    int wave = threadIdx.x >> 6, lane = threadIdx.x & 63;
    int lo = lane & 15, hi = lane >> 4;
    int m0 = blockIdx.x * 64 + wave * 16;

    f32x4 acc[16];
#pragma unroll
    for (int i = 0; i < 16; i++) acc[i] = (f32x4){0, 0, 0, 0};

    for (int ks = 0; ks < 8; ks++) {
        short8 a = *(const short8*)(O + (m0 + lo) * 256 + ks * 32 + hi * 8);
#pragma unroll
        for (int nf = 0; nf < 16; nf++) {
            short8 b = *(const short8*)(Wob + (nf * 16 + lo) * 256 + ks * 32 + hi * 8);
            acc[nf] = __builtin_amdgcn_mfma_f32_16x16x32_bf16(a, b, acc[nf], 0, 0, 0);
        }
    }
#pragma unroll
    for (int nf = 0; nf < 16; nf++)
#pragma unroll
        for (int r = 0; r < 4; r++) {
            int m = m0 + hi * 4 + r;
            int c = nf * 16 + lo;
            acc[nf][r] += bo[c] + bf2f(Vres[m * 256 + c]);
        }
    float sum[4];
#pragma unroll
    for (int r = 0; r < 4; r++) {
        float t = 0.f;
#pragma unroll
        for (int nf = 0; nf < 16; nf++) t += acc[nf][r];
        sum[r] = t;
    }
#pragma unroll
    for (int d = 1; d < 16; d <<= 1)
#pragma unroll
        for (int r = 0; r < 4; r++) sum[r] += __shfl_xor(sum[r], d, 64);
    float mean[4];
#pragma unroll
    for (int r = 0; r < 4; r++) mean[r] = sum[r] * (1.0f / 256.0f);

    float ss[4];
#pragma unroll
    for (int r = 0; r < 4; r++) {
        float t = 0.f;
#pragma unroll
        for (int nf = 0; nf < 16; nf++) {
            float d_ = acc[nf][r] - mean[r];
            t += d_ * d_;
        }
        ss[r] = t;
    }
#pragma unroll
    for (int d = 1; d < 16; d <<= 1)
#pragma unroll
        for (int r = 0; r < 4; r++) ss[r] += __shfl_xor(ss[r], d, 64);
    float rstd[4];
#pragma unroll
    for (int r = 0; r < 4; r++) rstd[r] = rsqrtf(ss[r] * (1.0f / 256.0f) + 1e-6f);

#pragma unroll
    for (int nf = 0; nf < 16; nf++)
#pragma unroll
        for (int r = 0; r < 4; r++) {
            int m = m0 + hi * 4 + r;
            int c = nf * 16 + lo;
            out[m * 256 + c] = (acc[nf][r] - mean[r]) * rstd[r] * gamma[c] + beta[c];
        }
}

// ---------------- launcher ----------------
extern "C" void kernel_launch(void* const* d_in, const int* in_sizes, int n_in,
                              void* d_out, int out_size, void* d_ws, size_t ws_size,
                              hipStream_t stream) {
    const float* x     = (const float*)d_in[0];
    const float* Wq    = (const float*)d_in[1];
    const float* bq    = (const float*)d_in[2];
    const float* Wk    = (const float*)d_in[3];
    const float* bk    = (const float*)d_in[4];
    const float* Wv    = (const float*)d_in[5];
    const float* bv    = (const float*)d_in[6];
    const float* Wo    = (const float*)d_in[7];
    const float* bo    = (const float*)d_in[8];
    const float* gamma = (const float*)d_in[9];
    const float* beta  = (const float*)d_in[10];
    float* out = (float*)d_out;

    char* ws = (char*)d_ws;
    short* xb   = (short*)(ws);                 // [16384][256] bf16   8.39 MB
    short* Qb   = (short*)(ws + 8388608);       // [32][4096][32]      8.39 MB
    short* Kb   = (short*)(ws + 16777216);      // [32][4096][32]      8.39 MB
    short* Vt   = (short*)(ws + 25165824);      // [32][32][4096]      8.39 MB
    short* Vres = (short*)(ws + 33554432);      // [16384][256]        8.39 MB
    short* Ob   = (short*)(ws + 41943040);      // [16384][256]        8.39 MB
    short* Wb   = (short*)(ws + 50331648);      // [4][256][256] bf16  512 KB
    short* Wob  = Wb + 3 * 65536;

    conv_x_kernel<<<2048, 256, 0, stream>>>(x, xb, 524288);
    conv_w_kernel<<<dim3(32, 4), 256, 0, stream>>>(Wq, Wk, Wv, Wo, Wb);
    qkv_kernel<<<dim3(256, 3), 256, 0, stream>>>(xb, Wb, bq, bk, bv, Qb, Kb, Vt, Vres);
    attn_kernel<<<2048, 256, 0, stream>>>(Qb, Kb, Vt, Ob);
    proj_ln_kernel<<<256, 256, 0, stream>>>(Ob, Wob, bo, Vres, gamma, beta, out);
}